// Round 1
// baseline (120.898 us; speedup 1.0000x reference)
//
#include <hip/hip_runtime.h>

// Attention_55336358642806: x@W_qkv+b -> 4-head causal attention -> @W_out+b
// B=16 S=1024 E=256 H=4 D=64.  All-MFMA bf16 pipeline, fp32 accumulation.
//
// ws layout (bytes):
//   [0, 393216)              W_qkvT bf16 [768][256]   (N-major, K contiguous)
//   [393216, 524288)         W_outT bf16 [256][256]
//   [524288, 25690112)       qkv    bf16 [16384][768] (attn out overwrites Q cols)

typedef unsigned short ushort_t;
typedef __bf16 bf16x8 __attribute__((ext_vector_type(8)));
typedef unsigned short u16x8 __attribute__((ext_vector_type(8)));
typedef float f32x4 __attribute__((ext_vector_type(4)));

__device__ __forceinline__ ushort_t f2bf(float f) {
  unsigned u = __builtin_bit_cast(unsigned, f);
  u += 0x7fffu + ((u >> 16) & 1u);   // round-to-nearest-even
  return (ushort_t)(u >> 16);
}

// ---------------- kernel 0: convert + transpose weights to bf16 -------------
__global__ __launch_bounds__(256)
void convert_wt(const float* __restrict__ Wq, const float* __restrict__ Wo,
                ushort_t* __restrict__ WqT, ushort_t* __restrict__ WoT)
{
  const int n = blockIdx.x;      // 0..1023: first 768 -> W_qkv cols, rest -> W_out cols
  const int k = threadIdx.x;     // 0..255
  if (n < 768) {
    WqT[n * 256 + k] = f2bf(Wq[(size_t)k * 768 + n]);
  } else {
    const int n2 = n - 768;
    WoT[n2 * 256 + k] = f2bf(Wo[(size_t)k * 256 + n2]);
  }
}

// ---------------- GEMM: C[M][N] = A[M][256] * Bt[N][256]^T + bias -----------
// Tile 64(M) x 128(N), BK=32, 4 waves (2x2), each wave 32x64 = 2x4 frags.
template<int A_F32, int OUT_F32>
__global__ __launch_bounds__(256)
void gemm_bias(const void* __restrict__ Ap, int ldA,
               const ushort_t* __restrict__ Bt,
               const float* __restrict__ bias,
               void* __restrict__ Outp, int ldOut)
{
  __shared__ ushort_t A_lds[64][40];    // stride 80B (16B-mult, conflict-benign)
  __shared__ ushort_t B_lds[128][40];

  const int tid = threadIdx.x;
  const int lane = tid & 63;
  const int w  = tid >> 6;
  const int wm = w >> 1, wn = w & 1;
  const int l15 = lane & 15, g = lane >> 4;
  const int m0 = blockIdx.y * 64;
  const int n0 = blockIdx.x * 128;

  f32x4 acc[2][4] = {};

  const int arow = tid >> 2, ac8  = (tid & 3) * 8;   // A: 64x32, 8 elems/thread
  const int brow = tid >> 1, bc16 = (tid & 1) * 16;  // B: 128x32, 16 elems/thread

  for (int k0 = 0; k0 < 256; k0 += 32) {
    __syncthreads();
    if (A_F32) {
      const float* A = (const float*)Ap;
      const float* src = &A[(size_t)(m0 + arow) * ldA + k0 + ac8];
      float4 v0 = *(const float4*)(src);
      float4 v1 = *(const float4*)(src + 4);
      u16x8 ov;
      ov[0]=f2bf(v0.x); ov[1]=f2bf(v0.y); ov[2]=f2bf(v0.z); ov[3]=f2bf(v0.w);
      ov[4]=f2bf(v1.x); ov[5]=f2bf(v1.y); ov[6]=f2bf(v1.z); ov[7]=f2bf(v1.w);
      *(u16x8*)&A_lds[arow][ac8] = ov;
    } else {
      const ushort_t* A = (const ushort_t*)Ap;
      *(u16x8*)&A_lds[arow][ac8] =
          *(const u16x8*)&A[(size_t)(m0 + arow) * ldA + k0 + ac8];
    }
    {
      const ushort_t* bsrc = &Bt[(size_t)(n0 + brow) * 256 + k0 + bc16];
      *(u16x8*)&B_lds[brow][bc16]     = *(const u16x8*)bsrc;
      *(u16x8*)&B_lds[brow][bc16 + 8] = *(const u16x8*)(bsrc + 8);
    }
    __syncthreads();

    bf16x8 af[2], bfrag[4];
    #pragma unroll
    for (int mi = 0; mi < 2; ++mi)
      af[mi] = __builtin_bit_cast(bf16x8,
                 *(const u16x8*)&A_lds[wm*32 + mi*16 + l15][g*8]);
    #pragma unroll
    for (int ni = 0; ni < 4; ++ni)
      bfrag[ni] = __builtin_bit_cast(bf16x8,
                 *(const u16x8*)&B_lds[wn*64 + ni*16 + l15][g*8]);
    #pragma unroll
    for (int mi = 0; mi < 2; ++mi)
      #pragma unroll
      for (int ni = 0; ni < 4; ++ni)
        acc[mi][ni] = __builtin_amdgcn_mfma_f32_16x16x32_bf16(
                          af[mi], bfrag[ni], acc[mi][ni], 0, 0, 0);
  }

  // epilogue: C/D layout row = g*4+r, col = l15 (HW-verified)
  #pragma unroll
  for (int mi = 0; mi < 2; ++mi)
    #pragma unroll
    for (int ni = 0; ni < 4; ++ni) {
      const int col = n0 + wn*64 + ni*16 + l15;
      const float bv = bias[col];
      #pragma unroll
      for (int r = 0; r < 4; ++r) {
        const int row = m0 + wm*32 + mi*16 + g*4 + r;
        const float v = acc[mi][ni][r] + bv;
        if (OUT_F32) ((float*)Outp)[(size_t)row * ldOut + col] = v;
        else         ((ushort_t*)Outp)[(size_t)row * ldOut + col] = f2bf(v);
      }
    }
}

// ---------------- kernel 2: causal flash attention --------------------------
// grid (qt=16, h=4, b=16), 256 thr = 4 waves; wave handles 16 q-rows.
// Output written into the Q columns of qkv (safe: each block reads its own Q
// into registers first; Q[row, head] is read/written by exactly one block).
__global__ __launch_bounds__(256)
void attn_kernel(ushort_t* qkv)
{
  const int qt = blockIdx.x;
  const int h  = blockIdx.y;
  const int b  = blockIdx.z;
  const int tid = threadIdx.x;
  const int lane = tid & 63;
  const int w = tid >> 6;
  const int l15 = lane & 15, g = lane >> 4;

  __shared__ ushort_t K_lds[64][72];      // [kv][d], stride 144B
  __shared__ ushort_t Vt_lds[64][72];     // [d][kv] (transposed)
  __shared__ ushort_t P_lds[4][16][72];   // per-wave P round-trip buffer

  const size_t rowbase = (size_t)b * 1024;
  const int qc = h * 64, kc = 256 + h * 64, vc = 512 + h * 64;

  // Q fragments (A-operand): row = l15 (wave-local), k(d) = ks*32 + g*8 + j
  bf16x8 qf[2];
  {
    const size_t qrow = rowbase + qt*64 + w*16 + l15;
    #pragma unroll
    for (int ks = 0; ks < 2; ++ks)
      qf[ks] = __builtin_bit_cast(bf16x8,
                 *(const u16x8*)&qkv[qrow*768 + qc + ks*32 + g*8]);
  }

  f32x4 o[4] = {};              // O accumulator, 4 d-frags (C layout)
  float m_run[4], l_run[4];
  #pragma unroll
  for (int r = 0; r < 4; ++r) { m_run[r] = -1e30f; l_run[r] = 0.f; }

  const int qrow0 = qt*64 + w*16 + g*4;   // + r = this lane's C-layout q rows

  const int krow = tid >> 2, kcc = (tid & 3) * 16;
  const int vkv  = tid & 63, vd0 = (tid >> 6) * 16;

  for (int kt = 0; kt <= qt; ++kt) {
    const int kv0 = kt * 64;
    __syncthreads();             // prev iter's K/Vt reads done
    {
      const ushort_t* src = &qkv[(rowbase + kv0 + krow)*768 + kc + kcc];
      *(u16x8*)&K_lds[krow][kcc]     = *(const u16x8*)src;
      *(u16x8*)&K_lds[krow][kcc + 8] = *(const u16x8*)(src + 8);
      const ushort_t* vsrc = &qkv[(rowbase + kv0 + vkv)*768 + vc + vd0];
      u16x8 v0 = *(const u16x8*)vsrc;
      u16x8 v1 = *(const u16x8*)(vsrc + 8);
      #pragma unroll
      for (int j = 0; j < 8; ++j) Vt_lds[vd0 + j][vkv] = v0[j];
      #pragma unroll
      for (int j = 0; j < 8; ++j) Vt_lds[vd0 + 8 + j][vkv] = v1[j];
    }
    __syncthreads();

    // S = Q K^T : B-frag n = kv (l15), k = d (g*8+j) -> K_lds rows contiguous
    f32x4 s[4] = {};
    #pragma unroll
    for (int ks = 0; ks < 2; ++ks)
      #pragma unroll
      for (int ni = 0; ni < 4; ++ni) {
        bf16x8 kf = __builtin_bit_cast(bf16x8,
                      *(const u16x8*)&K_lds[ni*16 + l15][ks*32 + g*8]);
        s[ni] = __builtin_amdgcn_mfma_f32_16x16x32_bf16(qf[ks], kf, s[ni], 0, 0, 0);
      }

    // scale + causal mask + online softmax (row = q, spread over 16 lanes x 4 frags)
    #pragma unroll
    for (int r = 0; r < 4; ++r) {
      const int qrow = qrow0 + r;
      float pv[4];
      float mx = -1e30f;
      #pragma unroll
      for (int ni = 0; ni < 4; ++ni) {
        const int kvg = kv0 + ni*16 + l15;
        float sc = s[ni][r] * 0.125f;                 // 1/sqrt(64)
        sc = (kvg <= qrow) ? sc : -1e30f;
        pv[ni] = sc;
        mx = fmaxf(mx, sc);
      }
      #pragma unroll
      for (int d = 1; d < 16; d <<= 1) mx = fmaxf(mx, __shfl_xor(mx, d));
      const float mnew  = fmaxf(m_run[r], mx);
      const float alpha = __expf(m_run[r] - mnew);
      float lsum = 0.f;
      #pragma unroll
      for (int ni = 0; ni < 4; ++ni) {
        const float p = __expf(pv[ni] - mnew);
        lsum += p;
        P_lds[w][g*4 + r][ni*16 + l15] = f2bf(p);     // C layout -> LDS
      }
      #pragma unroll
      for (int d = 1; d < 16; d <<= 1) lsum += __shfl_xor(lsum, d);
      m_run[r] = mnew;
      l_run[r] = l_run[r] * alpha + lsum;
      #pragma unroll
      for (int di = 0; di < 4; ++di) o[di][r] *= alpha;
    }
    __syncthreads();             // P visible (and K/Vt stage writers held back)

    // O += P V : A-frag from P_lds (row=l15, k=kv), B-frag from Vt (n=d, k=kv)
    #pragma unroll
    for (int ks = 0; ks < 2; ++ks) {
      bf16x8 pf = __builtin_bit_cast(bf16x8,
                    *(const u16x8*)&P_lds[w][l15][ks*32 + g*8]);
      #pragma unroll
      for (int di = 0; di < 4; ++di) {
        bf16x8 vf = __builtin_bit_cast(bf16x8,
                      *(const u16x8*)&Vt_lds[di*16 + l15][ks*32 + g*8]);
        o[di] = __builtin_amdgcn_mfma_f32_16x16x32_bf16(pf, vf, o[di], 0, 0, 0);
      }
    }
  }

  // normalize and write into Q columns of qkv
  #pragma unroll
  for (int r = 0; r < 4; ++r) {
    const float inv = 1.f / l_run[r];
    const size_t row = rowbase + qt*64 + w*16 + g*4 + r;
    #pragma unroll
    for (int di = 0; di < 4; ++di)
      qkv[row*768 + qc + di*16 + l15] = f2bf(o[di][r] * inv);
  }
}

// ---------------- launcher --------------------------------------------------
extern "C" void kernel_launch(void* const* d_in, const int* in_sizes, int n_in,
                              void* d_out, int out_size, void* d_ws, size_t ws_size,
                              hipStream_t stream)
{
  const float* x     = (const float*)d_in[0];   // [16,1024,256]
  const float* W_qkv = (const float*)d_in[1];   // [256,768]
  const float* b_qkv = (const float*)d_in[2];   // [768]
  const float* W_out = (const float*)d_in[3];   // [256,256]
  const float* b_out = (const float*)d_in[4];   // [256]
  float* out = (float*)d_out;                   // [16,1024,256] fp32

  char* ws = (char*)d_ws;
  ushort_t* WqT = (ushort_t*)ws;                              // [768][256]
  ushort_t* WoT = (ushort_t*)(ws + 768*256*2);                // [256][256]
  ushort_t* qkv = (ushort_t*)(ws + 768*256*2 + 256*256*2);    // [16384][768]
  // total ws use: ~25.7 MB

  convert_wt<<<dim3(1024), dim3(256), 0, stream>>>(W_qkv, W_out, WqT, WoT);
  // QKV projection: x[16384,256] * WqT^T + b_qkv -> qkv bf16
  gemm_bias<1, 0><<<dim3(6, 256), dim3(256), 0, stream>>>(
      x, 256, WqT, b_qkv, qkv, 768);
  // causal flash attention, writes result into Q columns of qkv
  attn_kernel<<<dim3(16, 4, 16), dim3(256), 0, stream>>>(qkv);
  // output projection: attn[16384,256](= qkv Q cols) * WoT^T + b_out -> out fp32
  gemm_bias<0, 1><<<dim3(2, 256), dim3(256), 0, stream>>>(
      qkv, 768, WoT, b_out, out, 256);
}